// Round 1
// baseline (73.631 us; speedup 1.0000x reference)
//
#include <hip/hip_runtime.h>
#include <hip/hip_bf16.h>
#include <type_traits>

#define AS1 __attribute__((address_space(1)))
#define AS3 __attribute__((address_space(3)))

typedef __attribute__((ext_vector_type(4))) float f32x4;
typedef __attribute__((ext_vector_type(8))) short bf16x8;

static constexpr int B_   = 2048;
static constexpr int IN_  = 1024;
static constexpr int HID_ = 2048;
static constexpr int NB_  = 8;
static constexpr int BS_  = 256;   // block size
static constexpr int G3_  = 768;   // 3*BS_

// ---------- fp32 -> bf16 (RNE) conversion ----------
__device__ __forceinline__ unsigned short f2bf(float f) {
  unsigned u = __builtin_bit_cast(unsigned, f);
  u = (u + 0x7FFFu + ((u >> 16) & 1u)) >> 16;
  return (unsigned short)u;
}

__global__ void cvt_kernel(const float* __restrict__ src,
                           unsigned short* __restrict__ dst, int n4) {
  int i = blockIdx.x * blockDim.x + threadIdx.x;
  int stride = gridDim.x * blockDim.x;
  for (; i < n4; i += stride) {
    float4 v = reinterpret_cast<const float4*>(src)[i];
    ushort4 o;
    o.x = f2bf(v.x); o.y = f2bf(v.y); o.z = f2bf(v.z); o.w = f2bf(v.w);
    reinterpret_cast<ushort4*>(dst)[i] = o;
  }
}

// ---------- fused block-GRU MFMA kernel ----------
// Tile: 64 batch rows x 64 block-cols per workgroup; 4 waves (2x2), 32x32/wave.
// Accumulators: [0]=r (K=1280 combined), [1]=z (combined), [2]=i_n (K=1024), [3]=h_n (K=256).
// LDS: A-tile [64][64]bf16 (8KB) + W-tile [192][64]bf16 (24KB), XOR-swizzled
// (phys = logical ^ ((row&7)<<4)); global_load_lds writes linearly so the
// global SOURCE address is pre-swizzled (guide rule #21).
__global__ __launch_bounds__(256) void gru_mfma(
    const unsigned short* __restrict__ inb,    // [2048][1024] bf16
    const unsigned short* __restrict__ hidb,   // [2048][2048] bf16
    const unsigned short* __restrict__ wihb,   // [8][768][1024] bf16
    const unsigned short* __restrict__ whhb,   // [8][768][256] bf16
    const float* __restrict__ hid_f32,         // [2048][2048] fp32 (for h_prev)
    const float* __restrict__ b_ih,            // [8][768]
    const float* __restrict__ b_hh,            // [8][768]
    float* __restrict__ out)                   // [2048][2048]
{
  __shared__ __align__(16) char Alds[8192];
  __shared__ __align__(16) char Wlds[24576];

  const int t    = threadIdx.x;
  const int lane = t & 63;
  const int wid  = t >> 6;
  const int wm   = wid >> 1;     // wave row (0..1)
  const int wn   = wid & 1;      // wave col (0..1)
  const int mrow0 = blockIdx.x * 64;
  const int ct    = blockIdx.y;
  const int n     = ct >> 2;          // GRU block index
  const int s0    = (ct & 3) * 64;    // col offset within block

  // Precompute swizzled staging coordinates.
  // Staging pass p writes phys LDS offset op = p*4096 + t*16; the element that
  // belongs there is logical ol = op ^ (((op>>7)&7)<<4) (involution, row bits
  // untouched).
  int arow[2], acb[2];
#pragma unroll
  for (int p = 0; p < 2; ++p) {
    int op = p * 4096 + t * 16;
    int ol = op ^ (((op >> 7) & 7) << 4);
    arow[p] = ol >> 7; acb[p] = ol & 127;
  }
  int wrowg[6], wsl[6], wcb[6];
#pragma unroll
  for (int p = 0; p < 6; ++p) {
    int op = p * 4096 + t * 16;
    int ol = op ^ (((op >> 7) & 7) << 4);
    int wr = ol >> 7;             // 0..191
    wrowg[p] = wr >> 6;           // gate 0..2
    wsl[p]   = wr & 63;           // col within 64-wide tile
    wcb[p]   = ol & 127;
  }

  f32x4 acc[4][2][2] = {};   // [set][mi][ni]

  auto kstep = [&](int ks, auto ph1c) {
    constexpr bool PH1 = decltype(ph1c)::value;
    __syncthreads();   // previous compute done before overwriting LDS
    // ---- stage A tile (64 x 64 bf16 = 8KB, 2 passes) ----
#pragma unroll
    for (int p = 0; p < 2; ++p) {
      const char* src;
      if constexpr (PH1) {
        src = (const char*)inb  + ((size_t)(mrow0 + arow[p]) * IN_  + ks * 64) * 2 + acb[p];
      } else {
        src = (const char*)hidb + ((size_t)(mrow0 + arow[p]) * HID_ + n * BS_ + ks * 64) * 2 + acb[p];
      }
      void* dst = Alds + p * 4096 + wid * 1024;   // wave-uniform base, lane*16 auto
      __builtin_amdgcn_global_load_lds((const AS1 void*)src, (AS3 void*)dst, 16, 0, 0);
    }
    // ---- stage W tile (192 x 64 bf16 = 24KB, 6 passes) ----
#pragma unroll
    for (int p = 0; p < 6; ++p) {
      int grow = n * G3_ + wrowg[p] * BS_ + s0 + wsl[p];
      const char* src;
      if constexpr (PH1) {
        src = (const char*)wihb + ((size_t)grow * IN_ + ks * 64) * 2 + wcb[p];
      } else {
        src = (const char*)whhb + ((size_t)grow * BS_ + ks * 64) * 2 + wcb[p];
      }
      void* dst = Wlds + p * 4096 + wid * 1024;
      __builtin_amdgcn_global_load_lds((const AS1 void*)src, (AS3 void*)dst, 16, 0, 0);
    }
    __syncthreads();   // compiler drains vmcnt before barrier
    // ---- MFMA: 2 K-substeps of 32 ----
#pragma unroll
    for (int ksub = 0; ksub < 2; ++ksub) {
      bf16x8 af[2];
#pragma unroll
      for (int mi = 0; mi < 2; ++mi) {
        int ar  = wm * 32 + mi * 16 + (lane & 15);
        int off = ar * 128 + ksub * 64 + ((lane >> 4) * 16);
        off ^= (ar & 7) << 4;
        af[mi] = *reinterpret_cast<const bf16x8*>(Alds + off);
      }
      bf16x8 wf[3][2];
#pragma unroll
      for (int g = 0; g < 3; ++g)
#pragma unroll
        for (int ni = 0; ni < 2; ++ni) {
          int wr  = g * 64 + wn * 32 + ni * 16 + (lane & 15);
          int off = wr * 128 + ksub * 64 + ((lane >> 4) * 16);
          off ^= (wr & 7) << 4;
          wf[g][ni] = *reinterpret_cast<const bf16x8*>(Wlds + off);
        }
#pragma unroll
      for (int mi = 0; mi < 2; ++mi)
#pragma unroll
        for (int ni = 0; ni < 2; ++ni) {
          acc[0][mi][ni] = __builtin_amdgcn_mfma_f32_16x16x32_bf16(af[mi], wf[0][ni], acc[0][mi][ni], 0, 0, 0);
          acc[1][mi][ni] = __builtin_amdgcn_mfma_f32_16x16x32_bf16(af[mi], wf[1][ni], acc[1][mi][ni], 0, 0, 0);
          if constexpr (PH1)
            acc[2][mi][ni] = __builtin_amdgcn_mfma_f32_16x16x32_bf16(af[mi], wf[2][ni], acc[2][mi][ni], 0, 0, 0);
          else
            acc[3][mi][ni] = __builtin_amdgcn_mfma_f32_16x16x32_bf16(af[mi], wf[2][ni], acc[3][mi][ni], 0, 0, 0);
        }
    }
  };

  for (int ks = 0; ks < 16; ++ks) kstep(ks, std::true_type{});   // K over input (1024)
#pragma unroll
  for (int ks = 0; ks < 4; ++ks) kstep(ks, std::false_type{});   // K over hidden block (256)

  // ---- epilogue: gates + output ----
#pragma unroll
  for (int ni = 0; ni < 2; ++ni) {
    int scol = s0 + wn * 32 + ni * 16 + (lane & 15);
    float br_i = b_ih[n * G3_ + 0 * BS_ + scol];
    float bz_i = b_ih[n * G3_ + 1 * BS_ + scol];
    float bn_i = b_ih[n * G3_ + 2 * BS_ + scol];
    float br_h = b_hh[n * G3_ + 0 * BS_ + scol];
    float bz_h = b_hh[n * G3_ + 1 * BS_ + scol];
    float bn_h = b_hh[n * G3_ + 2 * BS_ + scol];
    int gcol = n * BS_ + scol;
#pragma unroll
    for (int mi = 0; mi < 2; ++mi) {
#pragma unroll
      for (int i = 0; i < 4; ++i) {
        int row = mrow0 + wm * 32 + mi * 16 + (lane >> 4) * 4 + i;  // C/D: col=lane&15, row=(lane>>4)*4+reg
        float hprev = hid_f32[(size_t)row * HID_ + gcol];
        float rr = acc[0][mi][ni][i] + br_i + br_h;
        float zz = acc[1][mi][ni][i] + bz_i + bz_h;
        float r  = 1.f / (1.f + __expf(-rr));
        float z  = 1.f / (1.f + __expf(-zz));
        float ng = tanhf(acc[2][mi][ni][i] + bn_i + r * (acc[3][mi][ni][i] + bn_h));
        out[(size_t)row * HID_ + gcol] = (1.f - z) * ng + z * hprev;
      }
    }
  }
}

// ---------- fallback (only if ws too small): naive fp32 ----------
__global__ void gru_naive(const float* __restrict__ x, const float* __restrict__ h,
                          const float* __restrict__ Wih, const float* __restrict__ Whh,
                          const float* __restrict__ bih, const float* __restrict__ bhh,
                          float* __restrict__ out) {
  int b = blockIdx.x;
  int n = blockIdx.y;
  int s = threadIdx.x;   // 256
  __shared__ float xs[1024];
  __shared__ float hs[256];
  for (int i = threadIdx.x; i < 1024; i += 256) xs[i] = x[(size_t)b * IN_ + i];
  if (threadIdx.x < 256) hs[threadIdx.x] = h[(size_t)b * HID_ + n * BS_ + threadIdx.x];
  __syncthreads();
  float gi[3], gh[3];
  for (int g = 0; g < 3; ++g) {
    const float* w = Wih + ((size_t)(n * G3_ + g * BS_ + s)) * IN_;
    float a = 0.f;
    for (int k = 0; k < IN_; ++k) a += xs[k] * w[k];
    gi[g] = a + bih[n * G3_ + g * BS_ + s];
    const float* w2 = Whh + ((size_t)(n * G3_ + g * BS_ + s)) * BS_;
    float a2 = 0.f;
    for (int k = 0; k < BS_; ++k) a2 += hs[k] * w2[k];
    gh[g] = a2 + bhh[n * G3_ + g * BS_ + s];
  }
  float r = 1.f / (1.f + expf(-(gi[0] + gh[0])));
  float z = 1.f / (1.f + expf(-(gi[1] + gh[1])));
  float ng = tanhf(gi[2] + r * gh[2]);
  out[(size_t)b * HID_ + n * BS_ + s] = (1.f - z) * ng + z * hs[s];
}

extern "C" void kernel_launch(void* const* d_in, const int* in_sizes, int n_in,
                              void* d_out, int out_size, void* d_ws, size_t ws_size,
                              hipStream_t stream) {
  const float* x   = (const float*)d_in[0];
  const float* h   = (const float*)d_in[1];
  const float* Wih = (const float*)d_in[2];
  const float* Whh = (const float*)d_in[3];
  const float* bih = (const float*)d_in[4];
  const float* bhh = (const float*)d_in[5];
  float* out = (float*)d_out;

  const size_t szin  = (size_t)B_ * IN_;
  const size_t szhid = (size_t)B_ * HID_;
  const size_t szwih = (size_t)NB_ * G3_ * IN_;
  const size_t szwhh = (size_t)NB_ * G3_ * BS_;
  const size_t need  = (szin + szhid + szwih + szwhh) * 2;

  if (ws_size >= need) {
    unsigned short* inb  = (unsigned short*)d_ws;
    unsigned short* hidb = inb + szin;
    unsigned short* wihb = hidb + szhid;
    unsigned short* whhb = wihb + szwih;
    cvt_kernel<<<1024, 256, 0, stream>>>(x,   inb,  (int)(szin  / 4));
    cvt_kernel<<<2048, 256, 0, stream>>>(h,   hidb, (int)(szhid / 4));
    cvt_kernel<<<2048, 256, 0, stream>>>(Wih, wihb, (int)(szwih / 4));
    cvt_kernel<<<1024, 256, 0, stream>>>(Whh, whhb, (int)(szwhh / 4));
    dim3 grid(B_ / 64, HID_ / 64);
    gru_mfma<<<grid, 256, 0, stream>>>(inb, hidb, wihb, whhb, h, bih, bhh, out);
  } else {
    dim3 grid(B_, NB_);
    gru_naive<<<grid, 256, 0, stream>>>(x, h, Wih, Whh, bih, bhh, out);
  }
}

// Round 2
// 58.796 us; speedup vs baseline: 1.2523x; 1.2523x over previous
//
#include <hip/hip_runtime.h>
#include <hip/hip_bf16.h>
#include <type_traits>

#define AS1 __attribute__((address_space(1)))
#define AS3 __attribute__((address_space(3)))

typedef __attribute__((ext_vector_type(4))) float f32x4;
typedef __attribute__((ext_vector_type(8))) short bf16x8;

static constexpr int B_   = 2048;
static constexpr int IN_  = 1024;
static constexpr int HID_ = 2048;
static constexpr int NB_  = 8;
static constexpr int BS_  = 256;   // block size
static constexpr int G3_  = 768;   // 3*BS_

// ---------- fp32 -> bf16 (RNE) ----------
__device__ __forceinline__ unsigned short f2bf(float f) {
  unsigned u = __builtin_bit_cast(unsigned, f);
  u = (u + 0x7FFFu + ((u >> 16) & 1u)) >> 16;
  return (unsigned short)u;
}

// One launch converts all four fp32 arrays into the contiguous bf16 region in ws.
__global__ void cvt_all(const float* __restrict__ x, const float* __restrict__ h,
                        const float* __restrict__ Wih, const float* __restrict__ Whh,
                        unsigned short* __restrict__ dst) {
  constexpr int c0 = (B_ * IN_) / 4;                    // 524288
  constexpr int c1 = c0 + (B_ * HID_) / 4;              // 1572864
  constexpr int c2 = c1 + (NB_ * G3_ * IN_) / 4;        // 3145728
  constexpr int n4 = c2 + (NB_ * G3_ * BS_) / 4;        // 3538944
  int i = blockIdx.x * blockDim.x + threadIdx.x;
  int stride = gridDim.x * blockDim.x;
  for (; i < n4; i += stride) {
    float4 v;
    if (i < c0)       v = reinterpret_cast<const float4*>(x)[i];
    else if (i < c1)  v = reinterpret_cast<const float4*>(h)[i - c0];
    else if (i < c2)  v = reinterpret_cast<const float4*>(Wih)[i - c1];
    else              v = reinterpret_cast<const float4*>(Whh)[i - c2];
    ushort4 o;
    o.x = f2bf(v.x); o.y = f2bf(v.y); o.z = f2bf(v.z); o.w = f2bf(v.w);
    reinterpret_cast<ushort4*>(dst)[i] = o;
  }
}

// ---------- fused block-GRU MFMA kernel ----------
// Tile: 128 batch rows x 64 out-cols (192 gate cols); 4 waves (2x2), each wave
// 64 rows x 32 out-cols per gate-set.
// Accumulators: [0]=r (K=1280 combined), [1]=z (combined), [2]=i_n (K=1024), [3]=h_n (K=256).
// LDS: A-tile [128][64]bf16 (16KB) + W-tile [192][64]bf16 (24KB), XOR-swizzled
// (phys = logical ^ ((row&7)<<4)); global_load_lds writes linearly so the
// global SOURCE address is pre-swizzled (guide rule #21).
__global__ __launch_bounds__(256, 2) void gru_mfma(
    const unsigned short* __restrict__ inb,    // [2048][1024] bf16
    const unsigned short* __restrict__ hidb,   // [2048][2048] bf16
    const unsigned short* __restrict__ wihb,   // [8][768][1024] bf16
    const unsigned short* __restrict__ whhb,   // [8][768][256] bf16
    const float* __restrict__ hid_f32,         // [2048][2048] fp32 (h_prev)
    const float* __restrict__ b_ih,            // [8][768]
    const float* __restrict__ b_hh,            // [8][768]
    float* __restrict__ out)                   // [2048][2048]
{
  __shared__ __align__(16) char Alds[16384];
  __shared__ __align__(16) char Wlds[24576];

  const int t    = threadIdx.x;
  const int lane = t & 63;
  const int wid  = t >> 6;
  const int wm   = wid >> 1;     // wave row (0..1) -> 64-row half
  const int wn   = wid & 1;      // wave col (0..1) -> 32-col half
  const int mrow0 = blockIdx.x * 128;
  const int ct    = blockIdx.y;
  const int n     = ct >> 2;          // GRU block index
  const int s0    = (ct & 3) * 64;    // col offset within block

  // Staging pass p writes phys LDS offset op = p*4096 + t*16; element that
  // belongs there is logical ol = op ^ (((op>>7)&7)<<4) (involution).
  int arow[4], acb[4];
#pragma unroll
  for (int p = 0; p < 4; ++p) {
    int op = p * 4096 + t * 16;
    int ol = op ^ (((op >> 7) & 7) << 4);
    arow[p] = ol >> 7; acb[p] = ol & 127;
  }
  int wrowg[6], wsl[6], wcb[6];
#pragma unroll
  for (int p = 0; p < 6; ++p) {
    int op = p * 4096 + t * 16;
    int ol = op ^ (((op >> 7) & 7) << 4);
    int wr = ol >> 7;             // 0..191
    wrowg[p] = wr >> 6;           // gate 0..2
    wsl[p]   = wr & 63;           // col within 64-wide tile
    wcb[p]   = ol & 127;
  }

  f32x4 acc[4][4][2] = {};   // [set][mi][ni]

  auto kstep = [&](int ks, auto ph1c) {
    constexpr bool PH1 = decltype(ph1c)::value;
    __syncthreads();   // previous compute done before overwriting LDS
    // ---- stage A tile (128 x 64 bf16 = 16KB, 4 passes) ----
#pragma unroll
    for (int p = 0; p < 4; ++p) {
      const char* src;
      if constexpr (PH1) {
        src = (const char*)inb  + ((size_t)(mrow0 + arow[p]) * IN_  + ks * 64) * 2 + acb[p];
      } else {
        src = (const char*)hidb + ((size_t)(mrow0 + arow[p]) * HID_ + n * BS_ + ks * 64) * 2 + acb[p];
      }
      void* dst = Alds + p * 4096 + wid * 1024;
      __builtin_amdgcn_global_load_lds((const AS1 void*)src, (AS3 void*)dst, 16, 0, 0);
    }
    // ---- stage W tile (192 x 64 bf16 = 24KB, 6 passes) ----
#pragma unroll
    for (int p = 0; p < 6; ++p) {
      int grow = n * G3_ + wrowg[p] * BS_ + s0 + wsl[p];
      const char* src;
      if constexpr (PH1) {
        src = (const char*)wihb + ((size_t)grow * IN_ + ks * 64) * 2 + wcb[p];
      } else {
        src = (const char*)whhb + ((size_t)grow * BS_ + ks * 64) * 2 + wcb[p];
      }
      void* dst = Wlds + p * 4096 + wid * 1024;
      __builtin_amdgcn_global_load_lds((const AS1 void*)src, (AS3 void*)dst, 16, 0, 0);
    }
    __syncthreads();   // compiler drains vmcnt before barrier
    // ---- MFMA: 2 K-substeps of 32 ----
#pragma unroll
    for (int ksub = 0; ksub < 2; ++ksub) {
      bf16x8 af[4];
#pragma unroll
      for (int mi = 0; mi < 4; ++mi) {
        int ar  = wm * 64 + mi * 16 + (lane & 15);
        int off = ar * 128 + ksub * 64 + ((lane >> 4) * 16);
        off ^= (ar & 7) << 4;
        af[mi] = *reinterpret_cast<const bf16x8*>(Alds + off);
      }
#pragma unroll
      for (int g = 0; g < 3; ++g) {
        bf16x8 wf[2];
#pragma unroll
        for (int ni = 0; ni < 2; ++ni) {
          int wr  = g * 64 + wn * 32 + ni * 16 + (lane & 15);
          int off = wr * 128 + ksub * 64 + ((lane >> 4) * 16);
          off ^= (wr & 7) << 4;
          wf[ni] = *reinterpret_cast<const bf16x8*>(Wlds + off);
        }
        const int set = (g < 2) ? g : (PH1 ? 2 : 3);
#pragma unroll
        for (int mi = 0; mi < 4; ++mi)
#pragma unroll
          for (int ni = 0; ni < 2; ++ni)
            acc[set][mi][ni] = __builtin_amdgcn_mfma_f32_16x16x32_bf16(
                af[mi], wf[ni], acc[set][mi][ni], 0, 0, 0);
      }
    }
  };

  for (int ks = 0; ks < 16; ++ks) kstep(ks, std::true_type{});   // K over input (1024)
#pragma unroll
  for (int ks = 0; ks < 4; ++ks) kstep(ks, std::false_type{});   // K over hidden block (256)

  // ---- epilogue: gates + output ----
#pragma unroll
  for (int ni = 0; ni < 2; ++ni) {
    int scol = s0 + wn * 32 + ni * 16 + (lane & 15);
    float br_i = b_ih[n * G3_ + 0 * BS_ + scol];
    float bz_i = b_ih[n * G3_ + 1 * BS_ + scol];
    float bn_i = b_ih[n * G3_ + 2 * BS_ + scol];
    float br_h = b_hh[n * G3_ + 0 * BS_ + scol];
    float bz_h = b_hh[n * G3_ + 1 * BS_ + scol];
    float bn_h = b_hh[n * G3_ + 2 * BS_ + scol];
    int gcol = n * BS_ + scol;
#pragma unroll
    for (int mi = 0; mi < 4; ++mi) {
#pragma unroll
      for (int i = 0; i < 4; ++i) {
        int row = mrow0 + wm * 64 + mi * 16 + (lane >> 4) * 4 + i;  // C/D: col=lane&15, row=(lane>>4)*4+reg
        float hprev = hid_f32[(size_t)row * HID_ + gcol];
        float rr = acc[0][mi][ni][i] + br_i + br_h;
        float zz = acc[1][mi][ni][i] + bz_i + bz_h;
        float r  = 1.f / (1.f + __expf(-rr));
        float z  = 1.f / (1.f + __expf(-zz));
        float ng = tanhf(acc[2][mi][ni][i] + bn_i + r * (acc[3][mi][ni][i] + bn_h));
        out[(size_t)row * HID_ + gcol] = (1.f - z) * ng + z * hprev;
      }
    }
  }
}

// ---------- fallback (only if ws too small): naive fp32 ----------
__global__ void gru_naive(const float* __restrict__ x, const float* __restrict__ h,
                          const float* __restrict__ Wih, const float* __restrict__ Whh,
                          const float* __restrict__ bih, const float* __restrict__ bhh,
                          float* __restrict__ out) {
  int b = blockIdx.x;
  int n = blockIdx.y;
  int s = threadIdx.x;   // 256
  __shared__ float xs[1024];
  __shared__ float hs[256];
  for (int i = threadIdx.x; i < 1024; i += 256) xs[i] = x[(size_t)b * IN_ + i];
  if (threadIdx.x < 256) hs[threadIdx.x] = h[(size_t)b * HID_ + n * BS_ + threadIdx.x];
  __syncthreads();
  float gi[3], gh[3];
  for (int g = 0; g < 3; ++g) {
    const float* w = Wih + ((size_t)(n * G3_ + g * BS_ + s)) * IN_;
    float a = 0.f;
    for (int k = 0; k < IN_; ++k) a += xs[k] * w[k];
    gi[g] = a + bih[n * G3_ + g * BS_ + s];
    const float* w2 = Whh + ((size_t)(n * G3_ + g * BS_ + s)) * BS_;
    float a2 = 0.f;
    for (int k = 0; k < BS_; ++k) a2 += hs[k] * w2[k];
    gh[g] = a2 + bhh[n * G3_ + g * BS_ + s];
  }
  float r = 1.f / (1.f + expf(-(gi[0] + gh[0])));
  float z = 1.f / (1.f + expf(-(gi[1] + gh[1])));
  float ng = tanhf(gi[2] + r * gh[2]);
  out[(size_t)b * HID_ + n * BS_ + s] = (1.f - z) * ng + z * hs[s];
}

extern "C" void kernel_launch(void* const* d_in, const int* in_sizes, int n_in,
                              void* d_out, int out_size, void* d_ws, size_t ws_size,
                              hipStream_t stream) {
  const float* x   = (const float*)d_in[0];
  const float* h   = (const float*)d_in[1];
  const float* Wih = (const float*)d_in[2];
  const float* Whh = (const float*)d_in[3];
  const float* bih = (const float*)d_in[4];
  const float* bhh = (const float*)d_in[5];
  float* out = (float*)d_out;

  const size_t szin  = (size_t)B_ * IN_;
  const size_t szhid = (size_t)B_ * HID_;
  const size_t szwih = (size_t)NB_ * G3_ * IN_;
  const size_t szwhh = (size_t)NB_ * G3_ * BS_;
  const size_t need  = (szin + szhid + szwih + szwhh) * 2;

  if (ws_size >= need) {
    unsigned short* inb  = (unsigned short*)d_ws;
    unsigned short* hidb = inb + szin;
    unsigned short* wihb = hidb + szhid;
    unsigned short* whhb = wihb + szwih;
    cvt_all<<<2048, 256, 0, stream>>>(x, h, Wih, Whh, (unsigned short*)d_ws);
    dim3 grid(B_ / 128, HID_ / 64);
    gru_mfma<<<grid, 256, 0, stream>>>(inb, hidb, wihb, whhb, h, bih, bhh, out);
  } else {
    dim3 grid(B_, NB_);
    gru_naive<<<grid, 256, 0, stream>>>(x, h, Wih, Whh, bih, bhh, out);
  }
}